// Round 8
// baseline (510.376 us; speedup 1.0000x reference)
//
#include <hip/hip_runtime.h>
#include <hip/hip_cooperative_groups.h>

namespace cg = cooperative_groups;

typedef float float4v __attribute__((ext_vector_type(4)));
typedef float float2v __attribute__((ext_vector_type(2)));

__device__ __forceinline__ float sigm(float x) { return 1.0f / (1.0f + __expf(-x)); }

#define HS_LD 68   // padded leading dim (floats) for staged h in LDS

// ===========================================================================
// Shared device-function bodies (used by BOTH the cooperative mega kernel and
// the multi-kernel fallback path — identical arithmetic on both paths).
// ===========================================================================

// h0 = relu(nodes @ W_en + b_en); unit blk in [0,64)
__device__ __forceinline__ void encode_unit(int blk, int t,
    const float* __restrict__ nodes, const float* __restrict__ W_en,
    const float* __restrict__ b_en, float* __restrict__ h0)
{
    int idx = blk * 256 + t;                 // 16384 = B*N*D
    int d = idx & 63, bn = idx >> 6;
    const float* np_ = nodes + bn * 32;
    float acc = b_en[d];
#pragma unroll
    for (int k = 0; k < 32; ++k)
        acc = fmaf(np_[k], W_en[k * 64 + d], acc);
    h0[idx] = fmaxf(acc, 0.f);
}

// per-row active-edge compaction (ballot, ascending j: deterministic)
__device__ __forceinline__ void compact_unit(int blk, int t,
    const float* __restrict__ edges, int* __restrict__ rowcnt,
    int* __restrict__ rowlist)
{
    int row = blk * 4 + (t >> 6);            // 0..255 (= b*64 + i)
    int lane = t & 63;
    bool act = edges[((size_t)row * 64 + lane) * 16] != 0.f;
    unsigned long long m = __ballot(act);
    if (lane == 0) rowcnt[row] = __popcll(m);
    if (act) {
        int pos = __popcll(m & ((1ull << lane) - 1ull));
        rowlist[row * 64 + pos] = lane;
    }
}

// EW[p][d] = edges[p] @ W1b (W_r1 rows 64..79); unit u in [0,1024), 16 pairs
// smem needs >= 256 floats
__device__ __forceinline__ void ew_unit(int u, int t, float* smem,
    const float* __restrict__ edges, const float* __restrict__ W_r1,
    float* __restrict__ EW)
{
    __syncthreads();                         // smem reuse guard
    int base = u * 16;
    smem[t] = edges[(size_t)base * 16 + t];  // 16 pairs x 16 feats
    __syncthreads();
    int pp = t >> 7, d = t & 127;
#pragma unroll
    for (int pi = 0; pi < 8; ++pi) {
        int pl = pp * 8 + pi;
        float acc = 0.f;
#pragma unroll
        for (int k = 0; k < 16; ++k)
            acc = fmaf(smem[pl * 16 + k], W_r1[(64 + k) * 128 + d], acc);
        EW[(size_t)(base + pl) * 128 + d] = acc;
    }
}

// One aggregation unit: unit = (row-pair rg)<<3 | ic. smem >= 64*HS_LD floats.
__device__ __forceinline__ void phaseA_unit(int unit, int t, float* hs,
    const float* __restrict__ edges, const float* __restrict__ W_agg,
    const float* __restrict__ b_agg, const float* __restrict__ h_cur,
    const int* __restrict__ rowcnt, const int* __restrict__ rowlist,
    float* __restrict__ agg)
{
    int rg = unit >> 3, ic = unit & 7;
    int r0 = rg * 2;                   // two consecutive rows, same batch
    int b = r0 >> 6;
    int wv = t >> 6, lane = t & 63;
    int dim = ic * 8 + wv * 2 + (lane >> 5);
    int c2 = lane & 31;

    __syncthreads();                   // guard: previous phase's smem reads done
    {   // stage h[b] (64x64) into LDS, padded
        int n = t >> 2, seg = t & 3;
        const float* gp = h_cur + ((b << 6) + n) * 64 + seg * 16;
        float* lp = hs + n * HS_LD + seg * 16;
#pragma unroll
        for (int u = 0; u < 16; u += 4)
            *(float4v*)(lp + u) = *(const float4v*)(gp + u);
    }
    // resident W fragment: w[k] = W_agg[k][dim*64 + 2*c2 + {0,1}]
    float2v w[16];
    {
        const float* wp = W_agg + dim * 64 + c2 * 2;
#pragma unroll
        for (int k = 0; k < 16; ++k)
            w[k] = *(const float2v*)(wp + k * 4096);
    }
    float2v bias = *(const float2v*)(b_agg + dim * 64 + c2 * 2);
    __syncthreads();

    size_t ebase = ((size_t)b) << 12;
#pragma unroll
    for (int rr = 0; rr < 2; ++rr) {
        int row = r0 + rr;
        int ri = row & 63;
        int nE = rowcnt[row];          // wave-uniform
        float rsum = 0.f;

        int ejn = 0;
        float4v n0 = {0,0,0,0}, n1 = n0, n2 = n0, n3 = n0;
        if (nE > 0) {
            ejn = __builtin_amdgcn_readfirstlane(rowlist[row * 64]);
            const float* ep = edges + (ebase + (size_t)(ri * 64 + ejn)) * 16;
            n0 = *(const float4v*)ep;       n1 = *(const float4v*)(ep + 4);
            n2 = *(const float4v*)(ep + 8); n3 = *(const float4v*)(ep + 12);
        }
        for (int idx = 0; idx < nE; ++idx) {
            int ejc = ejn;
            float4v e0 = n0, e1 = n1, e2 = n2, e3 = n3;
            if (idx + 1 < nE) {
                ejn = __builtin_amdgcn_readfirstlane(rowlist[row * 64 + idx + 1]);
                const float* ep = edges + (ebase + (size_t)(ri * 64 + ejn)) * 16;
                n0 = *(const float4v*)ep;       n1 = *(const float4v*)(ep + 4);
                n2 = *(const float4v*)(ep + 8); n3 = *(const float4v*)(ep + 12);
            }
            float a0 = bias[0], a1 = bias[1];
#pragma unroll
            for (int k = 0; k < 4; ++k) { a0 = fmaf(e0[k], w[k][0], a0);      a1 = fmaf(e0[k], w[k][1], a1); }
#pragma unroll
            for (int k = 0; k < 4; ++k) { a0 = fmaf(e1[k], w[4 + k][0], a0);  a1 = fmaf(e1[k], w[4 + k][1], a1); }
#pragma unroll
            for (int k = 0; k < 4; ++k) { a0 = fmaf(e2[k], w[8 + k][0], a0);  a1 = fmaf(e2[k], w[8 + k][1], a1); }
#pragma unroll
            for (int k = 0; k < 4; ++k) { a0 = fmaf(e3[k], w[12 + k][0], a0); a1 = fmaf(e3[k], w[12 + k][1], a1); }
            float2v hv = *(const float2v*)(hs + ejc * HS_LD + c2 * 2);
            rsum = fmaf(fmaxf(a0, 0.f), hv[0], rsum);
            rsum = fmaf(fmaxf(a1, 0.f), hv[1], rsum);
        }
#pragma unroll
        for (int m = 1; m < 32; m <<= 1) rsum += __shfl_xor(rsum, m, 64);
        if (c2 == 0) agg[row * 64 + dim] = rsum;
    }
}

// Fused 2-cell GRU for one row; emits Ha/Hc on the last iteration.
// smem >= 832 floats.
__device__ __forceinline__ void gru_row(int row, int t, float* smem,
    const float* __restrict__ agg, const float* __restrict__ W_ih,
    const float* __restrict__ W_hh, const float* __restrict__ b_ih,
    const float* __restrict__ b_hh, const float* __restrict__ h_cur,
    float* __restrict__ h_next, const float* __restrict__ W_r1,
    const float* __restrict__ b_r1, float* __restrict__ Ha,
    float* __restrict__ Hc, int emit)
{
    float* hrow = smem;
    float* aggS = smem + 64;
    float* g1   = smem + 128;
    float* h1S  = smem + 320;
    float* g2i  = smem + 384;
    float* g2h  = smem + 576;
    float* hnS  = smem + 768;

    if (t < 64) hrow[t] = h_cur[row * 64 + t];
    if (t >= 64 && t < 128) aggS[t - 64] = agg[row * 64 + (t - 64)];
    __syncthreads();

    if (t < 192) {
        float g = b_ih[t];
        const float* wr = W_ih + t * 64;
#pragma unroll
        for (int k = 0; k < 64; ++k) g = fmaf(hrow[k], wr[k], g);
        g1[t] = g;
    }
    __syncthreads();
    if (t < 64) {
        float r1 = sigm(g1[t] + b_hh[t]);
        float z1 = sigm(g1[64 + t] + b_hh[64 + t]);
        float n1 = tanhf(g1[128 + t] + r1 * b_hh[128 + t]);
        h1S[t] = (1.f - z1) * n1;
    }
    __syncthreads();
    if (t < 192) {
        float gi = b_ih[t];
        float gh = b_hh[t];
        const float* wri = W_ih + t * 64;
        const float* wrh = W_hh + t * 64;
#pragma unroll
        for (int k = 0; k < 64; ++k) {
            gi = fmaf(aggS[k], wri[k], gi);
            gh = fmaf(h1S[k], wrh[k], gh);
        }
        g2i[t] = gi; g2h[t] = gh;
    }
    __syncthreads();
    if (t < 64) {
        float r = sigm(g2i[t] + g2h[t]);
        float z = sigm(g2i[64 + t] + g2h[64 + t]);
        float n = tanhf(g2i[128 + t] + r * g2h[128 + t]);
        float hn = (1.f - z) * n + z * h1S[t];
        h_next[row * 64 + t] = hn;
        hnS[t] = hn;
    }
    __syncthreads();
    if (emit) {
        // Ha = h @ W1a + b_r1 ; Hc = h @ W1c  (readout layer-1 node terms)
        int m = t >> 7, d = t & 127;
        const float* wbase = W_r1 + (m ? 80 * 128 : 0) + d;
        float acc = m ? 0.f : b_r1[d];
#pragma unroll
        for (int k = 0; k < 64; ++k)
            acc = fmaf(hnS[k], wbase[k * 128], acc);
        if (m == 0) Ha[row * 128 + d] = acc;
        else        Hc[row * 128 + d] = acc;
    }
}

// Factored readout, 16 pairs per unit: unit = row*4 + qp. smem >= 2176 floats.
__device__ __forceinline__ void readout_unit(int unit, int t, float* smem,
    const float* __restrict__ EW, const float* __restrict__ Ha,
    const float* __restrict__ Hc, const float* __restrict__ W_r2,
    const float* __restrict__ b_r2, const float* __restrict__ W_r3,
    const float* __restrict__ b_r3, float* __restrict__ out)
{
    float* HaS = smem;          // 128
    float* A1  = smem + 128;    // 16 x 128 (Hc staged, then a1 in place)
    int row = unit >> 2, qp = unit & 3;
    int b = row >> 6;

    __syncthreads();            // smem reuse guard
    const float* src = Hc + (size_t)((b << 6) + qp * 16) * 128;
#pragma unroll
    for (int r = 0; r < 2; ++r) {
        int off = (r * 256 + t) * 4;
        *(float4v*)(A1 + off) = *(const float4v*)(src + off);
    }
    if (t < 32)
        *(float4v*)(HaS + t * 4) = *(const float4v*)(Ha + (size_t)row * 128 + t * 4);
    __syncthreads();

    // layer 1: a1 = relu(Ha[i] + Hc[j] + EW[p])  (in place, same-thread)
    const float* EWrow = EW + (size_t)(row * 64 + qp * 16) * 128;
#pragma unroll
    for (int r = 0; r < 2; ++r) {
        int off = (r * 256 + t) * 4;
        int dd = off & 127;
        float4v hc = *(const float4v*)(A1 + off);
        float4v ha = *(const float4v*)(HaS + dd);
        float4v ew = *(const float4v*)(EWrow + off);
        float4v a;
#pragma unroll
        for (int u = 0; u < 4; ++u) a[u] = fmaxf(hc[u] + ha[u] + ew[u], 0.f);
        *(float4v*)(A1 + off) = a;
    }
    __syncthreads();

    // layer 2: 2 pairs x 4 dims per thread; a1 reads are broadcasts
    int td = t & 31, pg = t >> 5;
    float4v bb2 = *(const float4v*)(b_r2 + td * 4);
    float4v acc0 = bb2, acc1 = bb2;
    for (int k4 = 0; k4 < 32; ++k4) {
        float4v w0 = *(const float4v*)(W_r2 + (k4 * 4 + 0) * 128 + td * 4);
        float4v w1 = *(const float4v*)(W_r2 + (k4 * 4 + 1) * 128 + td * 4);
        float4v w2 = *(const float4v*)(W_r2 + (k4 * 4 + 2) * 128 + td * 4);
        float4v w3_ = *(const float4v*)(W_r2 + (k4 * 4 + 3) * 128 + td * 4);
        float4v a0 = *(const float4v*)(A1 + (pg * 2 + 0) * 128 + k4 * 4);
        float4v a1v = *(const float4v*)(A1 + (pg * 2 + 1) * 128 + k4 * 4);
#pragma unroll
        for (int u = 0; u < 4; ++u) {
            acc0[u] = fmaf(a0[0], w0[u], acc0[u]);
            acc0[u] = fmaf(a0[1], w1[u], acc0[u]);
            acc0[u] = fmaf(a0[2], w2[u], acc0[u]);
            acc0[u] = fmaf(a0[3], w3_[u], acc0[u]);
            acc1[u] = fmaf(a1v[0], w0[u], acc1[u]);
            acc1[u] = fmaf(a1v[1], w1[u], acc1[u]);
            acc1[u] = fmaf(a1v[2], w2[u], acc1[u]);
            acc1[u] = fmaf(a1v[3], w3_[u], acc1[u]);
        }
    }

    // layer 3: dot(relu(a2), w3), reduce over 32 dim-threads
    float4v w3v = *(const float4v*)(W_r3 + td * 4);
    float b3 = b_r3[0];
    float p0 = fmaxf(acc0[0], 0.f) * w3v[0] + fmaxf(acc0[1], 0.f) * w3v[1]
             + fmaxf(acc0[2], 0.f) * w3v[2] + fmaxf(acc0[3], 0.f) * w3v[3];
    float p1 = fmaxf(acc1[0], 0.f) * w3v[0] + fmaxf(acc1[1], 0.f) * w3v[1]
             + fmaxf(acc1[2], 0.f) * w3v[2] + fmaxf(acc1[3], 0.f) * w3v[3];
#pragma unroll
    for (int m = 1; m < 32; m <<= 1) {
        p0 += __shfl_xor(p0, m, 64);
        p1 += __shfl_xor(p1, m, 64);
    }
    if (td == 0) {
        out[row * 64 + qp * 16 + pg * 2 + 0] = p0 + b3;
        out[row * 64 + qp * 16 + pg * 2 + 1] = p1 + b3;
    }
}

// ===========================================================================
// Cooperative mega kernel: 512 blocks x 256 thr (needs only 2 blocks/CU
// co-resident — big occupancy margin). Each phase processes 2 units/block.
// ===========================================================================
__global__ __launch_bounds__(256, 4) void k_mega(
    const float* __restrict__ edges, const float* __restrict__ nodes,
    const float* __restrict__ W_en, const float* __restrict__ b_en,
    const float* __restrict__ W_agg, const float* __restrict__ b_agg,
    const float* __restrict__ W_ih, const float* __restrict__ W_hh,
    const float* __restrict__ b_ih, const float* __restrict__ b_hh,
    const float* __restrict__ W_r1, const float* __restrict__ b_r1,
    const float* __restrict__ W_r2, const float* __restrict__ b_r2,
    const float* __restrict__ W_r3, const float* __restrict__ b_r3,
    int* __restrict__ rowcnt, int* __restrict__ rowlist,
    float* __restrict__ agg, float* __restrict__ hA, float* __restrict__ hB,
    float* __restrict__ Ha, float* __restrict__ Hc, float* __restrict__ EW,
    float* __restrict__ out)
{
    cg::grid_group grid = cg::this_grid();
    __shared__ float smem[64 * HS_LD];   // 17.4 KB, phase-aliased
    int t = threadIdx.x, blk = blockIdx.x;   // 512 blocks

    // P0: encode / compaction / EW
    if (blk < 64)       encode_unit(blk, t, nodes, W_en, b_en, hA);
    else if (blk < 128) compact_unit(blk - 64, t, edges, rowcnt, rowlist);
    ew_unit(blk,       t, smem, edges, W_r1, EW);
    ew_unit(blk + 512, t, smem, edges, W_r1, EW);
    grid.sync();

    // T = 3 message-passing steps
    for (int it = 0; it < 3; ++it) {
        const float* h_cur = (it & 1) ? hB : hA;
        float* h_next      = (it & 1) ? hA : hB;
        phaseA_unit(blk,       t, smem, edges, W_agg, b_agg, h_cur, rowcnt, rowlist, agg);
        phaseA_unit(blk + 512, t, smem, edges, W_agg, b_agg, h_cur, rowcnt, rowlist, agg);
        grid.sync();
        if (blk < 256)
            gru_row(blk, t, smem, agg, W_ih, W_hh, b_ih, b_hh, h_cur, h_next,
                    W_r1, b_r1, Ha, Hc, it == 2);
        grid.sync();
    }

    // readout
    readout_unit(blk,       t, smem, EW, Ha, Hc, W_r2, b_r2, W_r3, b_r3, out);
    readout_unit(blk + 512, t, smem, EW, Ha, Hc, W_r2, b_r2, W_r3, b_r3, out);
}

// ===========================================================================
// Fallback multi-kernel path (identical math via the same device functions).
// ===========================================================================
__global__ __launch_bounds__(256) void k_preK(
    const float* __restrict__ nodes, const float* __restrict__ W_en,
    const float* __restrict__ b_en, const float* __restrict__ edges,
    const float* __restrict__ W_r1, float* __restrict__ h0,
    int* __restrict__ rowcnt, int* __restrict__ rowlist, float* __restrict__ EW)
{
    __shared__ float smem[256];
    int t = threadIdx.x;
    if (blockIdx.x < 64)       encode_unit(blockIdx.x, t, nodes, W_en, b_en, h0);
    else if (blockIdx.x < 128) compact_unit(blockIdx.x - 64, t, edges, rowcnt, rowlist);
    else                       ew_unit(blockIdx.x - 128, t, smem, edges, W_r1, EW);
}

__global__ __launch_bounds__(256, 4) void k_iterK(
    const float* __restrict__ edges, const float* __restrict__ W_agg,
    const float* __restrict__ b_agg, const float* __restrict__ h_cur,
    const int* __restrict__ rowcnt, const int* __restrict__ rowlist,
    float* __restrict__ agg)
{
    __shared__ float smem[64 * HS_LD];
    phaseA_unit(blockIdx.x, threadIdx.x, smem, edges, W_agg, b_agg, h_cur,
                rowcnt, rowlist, agg);
}

__global__ __launch_bounds__(256) void k_gruK(
    const float* __restrict__ agg, const float* __restrict__ W_ih,
    const float* __restrict__ W_hh, const float* __restrict__ b_ih,
    const float* __restrict__ b_hh, const float* __restrict__ h_cur,
    float* __restrict__ h_next, const float* __restrict__ W_r1,
    const float* __restrict__ b_r1, float* __restrict__ Ha,
    float* __restrict__ Hc, int emit)
{
    __shared__ float smem[832];
    gru_row(blockIdx.x, threadIdx.x, smem, agg, W_ih, W_hh, b_ih, b_hh,
            h_cur, h_next, W_r1, b_r1, Ha, Hc, emit);
}

__global__ __launch_bounds__(256) void k_readK(
    const float* __restrict__ EW, const float* __restrict__ Ha,
    const float* __restrict__ Hc, const float* __restrict__ W_r2,
    const float* __restrict__ b_r2, const float* __restrict__ W_r3,
    const float* __restrict__ b_r3, float* __restrict__ out)
{
    __shared__ float smem[2176];
    readout_unit(blockIdx.x, threadIdx.x, smem, EW, Ha, Hc, W_r2, b_r2,
                 W_r3, b_r3, out);
}

// ---------------------------------------------------------------------------
extern "C" void kernel_launch(void* const* d_in, const int* in_sizes, int n_in,
                              void* d_out, int out_size, void* d_ws, size_t ws_size,
                              hipStream_t stream)
{
    const float* edges = (const float*)d_in[0];
    const float* nodes = (const float*)d_in[1];
    // d_in[2] adjacency: unused
    const float* W_en  = (const float*)d_in[3];
    const float* b_en  = (const float*)d_in[4];
    const float* W_agg = (const float*)d_in[5];
    const float* b_agg = (const float*)d_in[6];
    const float* W_ih  = (const float*)d_in[7];
    const float* W_hh  = (const float*)d_in[8];
    const float* b_ih  = (const float*)d_in[9];
    const float* b_hh  = (const float*)d_in[10];
    const float* W_r1  = (const float*)d_in[11];
    const float* b_r1  = (const float*)d_in[12];
    const float* W_r2  = (const float*)d_in[13];
    const float* b_r2  = (const float*)d_in[14];
    const float* W_r3  = (const float*)d_in[15];
    const float* b_r3  = (const float*)d_in[16];

    // workspace layout (~8.7 MB, fully rewritten every call)
    int*   rowcnt  = (int*)d_ws;                         // 256
    int*   rowlist = rowcnt + 256;                       // 16384
    float* agg     = (float*)(rowlist + 16384);          // 16384
    float* hA      = agg + 16384;                        // 16384
    float* hB      = hA + 16384;                         // 16384
    float* Ha      = hB + 16384;                         // 256*128
    float* Hc      = Ha + 256 * 128;                     // 256*128
    float* EW      = Hc + 256 * 128;                     // 16384*128
    float* out     = (float*)d_out;

    // --- try cooperative single-kernel path (host-side queries only:
    //     capture-safe, no stream ops, deterministic every call) ---
    hipError_t err = hipErrorUnknown;
    int maxblk = 0, cus = 0, dev = 0;
    if (hipGetDevice(&dev) == hipSuccess &&
        hipDeviceGetAttribute(&cus, hipDeviceAttributeMultiprocessorCount, dev) == hipSuccess &&
        hipOccupancyMaxActiveBlocksPerMultiprocessor(&maxblk, (const void*)k_mega, 256, 0) == hipSuccess &&
        (long)maxblk * (long)cus >= 512) {
        void* args[] = {
            (void*)&edges, (void*)&nodes, (void*)&W_en, (void*)&b_en,
            (void*)&W_agg, (void*)&b_agg, (void*)&W_ih, (void*)&W_hh,
            (void*)&b_ih, (void*)&b_hh, (void*)&W_r1, (void*)&b_r1,
            (void*)&W_r2, (void*)&b_r2, (void*)&W_r3, (void*)&b_r3,
            (void*)&rowcnt, (void*)&rowlist, (void*)&agg, (void*)&hA, (void*)&hB,
            (void*)&Ha, (void*)&Hc, (void*)&EW, (void*)&out
        };
        err = hipLaunchCooperativeKernel((const void*)k_mega, dim3(512), dim3(256),
                                         args, 0, stream);
    }

    if (err != hipSuccess) {
        // --- fallback: proven multi-kernel pipeline, same device functions ---
        k_preK<<<1152, 256, 0, stream>>>(nodes, W_en, b_en, edges, W_r1,
                                         hA, rowcnt, rowlist, EW);
        k_iterK<<<1024, 256, 0, stream>>>(edges, W_agg, b_agg, hA, rowcnt, rowlist, agg);
        k_gruK<<<256, 256, 0, stream>>>(agg, W_ih, W_hh, b_ih, b_hh, hA, hB,
                                        W_r1, b_r1, Ha, Hc, 0);
        k_iterK<<<1024, 256, 0, stream>>>(edges, W_agg, b_agg, hB, rowcnt, rowlist, agg);
        k_gruK<<<256, 256, 0, stream>>>(agg, W_ih, W_hh, b_ih, b_hh, hB, hA,
                                        W_r1, b_r1, Ha, Hc, 0);
        k_iterK<<<1024, 256, 0, stream>>>(edges, W_agg, b_agg, hA, rowcnt, rowlist, agg);
        k_gruK<<<256, 256, 0, stream>>>(agg, W_ih, W_hh, b_ih, b_hh, hA, hB,
                                        W_r1, b_r1, Ha, Hc, 1);
        k_readK<<<1024, 256, 0, stream>>>(EW, Ha, Hc, W_r2, b_r2, W_r3, b_r3, out);
    }
}

// Round 9
// 105.195 us; speedup vs baseline: 4.8517x; 4.8517x over previous
//
#include <hip/hip_runtime.h>

typedef float float4v __attribute__((ext_vector_type(4)));

__device__ __forceinline__ float sigm(float x) { return 1.0f / (1.0f + __expf(-x)); }

#define HS_LD 68   // padded leading dim (floats) for staged h in LDS

// ---------------------------------------------------------------------------
// k_pre: blocks 0..63    -> h0 = relu(nodes @ W_en + b_en)
//        blocks 64..127  -> per-row active-edge compaction (ballot)
//        blocks 128..1151-> EW[p][d] = edges[p] @ W1b (W_r1 rows 64..79)
__global__ __launch_bounds__(256) void k_pre(
    const float* __restrict__ nodes, const float* __restrict__ W_en,
    const float* __restrict__ b_en, const float* __restrict__ edges,
    const float* __restrict__ W_r1,
    float* __restrict__ h0, int* __restrict__ rowcnt, int* __restrict__ rowlist,
    float* __restrict__ EW)
{
    __shared__ float eS[256];
    int t = threadIdx.x;
    if (blockIdx.x < 64) {
        int idx = blockIdx.x * 256 + t;          // 16384 = B*N*D
        int d = idx & 63, bn = idx >> 6;
        const float* np_ = nodes + bn * 32;
        float acc = b_en[d];
#pragma unroll
        for (int k = 0; k < 32; ++k)
            acc = fmaf(np_[k], W_en[k * 64 + d], acc);
        h0[idx] = fmaxf(acc, 0.f);
    } else if (blockIdx.x < 128) {
        int row = (blockIdx.x - 64) * 4 + (t >> 6);
        int lane = t & 63;
        bool act = edges[((size_t)row * 64 + lane) * 16] != 0.f;
        unsigned long long m = __ballot(act);
        if (lane == 0) rowcnt[row] = __popcll(m);
        if (act) {
            int pos = __popcll(m & ((1ull << lane) - 1ull));
            rowlist[row * 64 + pos] = lane;      // ascending j: deterministic
        }
    } else {
        int base = (blockIdx.x - 128) * 16;      // 16 pairs per block
        eS[t] = edges[(size_t)base * 16 + t];
        __syncthreads();
        int pp = t >> 7, d = t & 127;
#pragma unroll
        for (int pi = 0; pi < 8; ++pi) {
            int pl = pp * 8 + pi;
            float acc = 0.f;
#pragma unroll
            for (int k = 0; k < 16; ++k)
                acc = fmaf(eS[pl * 16 + k], W_r1[(64 + k) * 128 + d], acc);
            EW[(size_t)(base + pl) * 128 + d] = acc;
        }
    }
}

// ---------------------------------------------------------------------------
// Fused iteration kernel: ONE block = ONE receiver row (b,i). 512 threads.
//   agg[dim] = sum_{j active} relu(edges[row,j] @ W_agg + b_agg)[dim,:] . h[b,j]
//   then in-block: h1 = GRU(h_row, 0); h_next = GRU(agg, h1)   (+ Ha/Hc emit)
// Lane layout: wave wv (8), lane: dim0 = wv*4 + (lane>>4), dim1 = dim0+32,
// c4 = lane&15 -> A-columns c4*4..+3. Both dims' W fragments in registers
// (128 VGPR); edge features are wave-uniform scalar loads; h via one
// ds_read_b128 per edge (broadcast across the 4 same-c4 lane groups).
__global__ __launch_bounds__(512, 2) void k_ig(
    const float* __restrict__ edges, const float* __restrict__ W_agg,
    const float* __restrict__ b_agg,
    const float* __restrict__ W_ih, const float* __restrict__ W_hh,
    const float* __restrict__ b_ih, const float* __restrict__ b_hh,
    const int* __restrict__ rowcnt, const int* __restrict__ rowlist,
    const float* __restrict__ h_cur, float* __restrict__ h_next,
    const float* __restrict__ W_r1, const float* __restrict__ b_r1,
    float* __restrict__ Ha, float* __restrict__ Hc, int emit)
{
    __shared__ float hs[64 * HS_LD];   // h of this batch (17.4 KB)
    __shared__ float xtra[768];        // aggS|g1|h1S|g2i|g2h|hnS

    int t = threadIdx.x;
    int row = blockIdx.x;              // 0..255 = b*64 + i
    int ri = row & 63;
    int b = row >> 6;

    // stage h[b] (64x64) into padded LDS: thread t -> row t>>3, cols (t&7)*8
    {
        int n = t >> 3, col = (t & 7) * 8;
        const float* gp = h_cur + ((b << 6) + n) * 64 + col;
        float* lp = hs + n * HS_LD + col;
        *(float4v*)(lp)     = *(const float4v*)(gp);
        *(float4v*)(lp + 4) = *(const float4v*)(gp + 4);
    }

    int wv = t >> 6, lane = t & 63;
    int dim0 = wv * 4 + (lane >> 4);   // 0..31
    int dim1 = dim0 + 32;              // 32..63
    int c4 = lane & 15;                // columns c4*4 .. c4*4+3

    // resident W fragments for both dims (64+64 floats)
    float4v w0[16], w1[16];
    {
        const float* wp0 = W_agg + dim0 * 64 + c4 * 4;
        const float* wp1 = W_agg + dim1 * 64 + c4 * 4;
#pragma unroll
        for (int k = 0; k < 16; ++k) {
            w0[k] = *(const float4v*)(wp0 + k * 4096);
            w1[k] = *(const float4v*)(wp1 + k * 4096);
        }
    }
    float4v bias0 = *(const float4v*)(b_agg + dim0 * 64 + c4 * 4);
    float4v bias1 = *(const float4v*)(b_agg + dim1 * 64 + c4 * 4);

    __syncthreads();

    // ---- edge loop (wave-uniform scalar streaming, 1-deep pipeline) ----
    int nE = rowcnt[row];
    float rsum0 = 0.f, rsum1 = 0.f;
    size_t ebase = ((size_t)b) << 12;

    int ejn = 0;
    float4v n0 = {0,0,0,0}, n1 = n0, n2 = n0, n3 = n0;
    if (nE > 0) {
        ejn = __builtin_amdgcn_readfirstlane(rowlist[row * 64]);
        const float* ep = edges + (ebase + (size_t)(ri * 64 + ejn)) * 16;
        n0 = *(const float4v*)ep;       n1 = *(const float4v*)(ep + 4);
        n2 = *(const float4v*)(ep + 8); n3 = *(const float4v*)(ep + 12);
    }
    for (int idx = 0; idx < nE; ++idx) {
        int ejc = ejn;
        float4v e0 = n0, e1 = n1, e2 = n2, e3 = n3;
        if (idx + 1 < nE) {
            ejn = __builtin_amdgcn_readfirstlane(rowlist[row * 64 + idx + 1]);
            const float* ep = edges + (ebase + (size_t)(ri * 64 + ejn)) * 16;
            n0 = *(const float4v*)ep;       n1 = *(const float4v*)(ep + 4);
            n2 = *(const float4v*)(ep + 8); n3 = *(const float4v*)(ep + 12);
        }
        float4v a0 = bias0, a1 = bias1;
#pragma unroll
        for (int k = 0; k < 4; ++k) {
#pragma unroll
            for (int u = 0; u < 4; ++u) {
                a0[u] = fmaf(e0[k], w0[k][u], a0[u]);
                a1[u] = fmaf(e0[k], w1[k][u], a1[u]);
            }
        }
#pragma unroll
        for (int k = 0; k < 4; ++k) {
#pragma unroll
            for (int u = 0; u < 4; ++u) {
                a0[u] = fmaf(e1[k], w0[4 + k][u], a0[u]);
                a1[u] = fmaf(e1[k], w1[4 + k][u], a1[u]);
            }
        }
#pragma unroll
        for (int k = 0; k < 4; ++k) {
#pragma unroll
            for (int u = 0; u < 4; ++u) {
                a0[u] = fmaf(e2[k], w0[8 + k][u], a0[u]);
                a1[u] = fmaf(e2[k], w1[8 + k][u], a1[u]);
            }
        }
#pragma unroll
        for (int k = 0; k < 4; ++k) {
#pragma unroll
            for (int u = 0; u < 4; ++u) {
                a0[u] = fmaf(e3[k], w0[12 + k][u], a0[u]);
                a1[u] = fmaf(e3[k], w1[12 + k][u], a1[u]);
            }
        }
        float4v hv = *(const float4v*)(hs + ejc * HS_LD + c4 * 4);
#pragma unroll
        for (int u = 0; u < 4; ++u) {
            rsum0 = fmaf(fmaxf(a0[u], 0.f), hv[u], rsum0);
            rsum1 = fmaf(fmaxf(a1[u], 0.f), hv[u], rsum1);
        }
    }
    // reduce over the 16 c4-lanes of each dim group
#pragma unroll
    for (int m = 1; m < 16; m <<= 1) {
        rsum0 += __shfl_xor(rsum0, m, 64);
        rsum1 += __shfl_xor(rsum1, m, 64);
    }
    float* aggS = xtra;                // 64
    if (c4 == 0) { aggS[dim0] = rsum0; aggS[dim1] = rsum1; }
    __syncthreads();

    // ---- fused 2-cell GRU (threads 0..191 active per stage) ----
    float* g1  = xtra + 64;            // 192
    float* h1S = xtra + 256;           // 64
    float* g2i = xtra + 320;           // 192
    float* g2h = xtra + 512;           // 192
    float* hnS = xtra + 704;           // 64
    const float* hrow = hs + ri * HS_LD;

    if (t < 192) {
        float g = b_ih[t];
        const float* wr = W_ih + t * 64;
#pragma unroll
        for (int k = 0; k < 64; ++k) g = fmaf(hrow[k], wr[k], g);
        g1[t] = g;
    }
    __syncthreads();
    if (t < 64) {
        float r1 = sigm(g1[t] + b_hh[t]);
        float z1 = sigm(g1[64 + t] + b_hh[64 + t]);
        float nn1 = tanhf(g1[128 + t] + r1 * b_hh[128 + t]);
        h1S[t] = (1.f - z1) * nn1;
    }
    __syncthreads();
    if (t < 192) {
        float gi = b_ih[t];
        float gh = b_hh[t];
        const float* wri = W_ih + t * 64;
        const float* wrh = W_hh + t * 64;
#pragma unroll
        for (int k = 0; k < 64; ++k) {
            gi = fmaf(aggS[k], wri[k], gi);
            gh = fmaf(h1S[k], wrh[k], gh);
        }
        g2i[t] = gi; g2h[t] = gh;
    }
    __syncthreads();
    if (t < 64) {
        float r = sigm(g2i[t] + g2h[t]);
        float z = sigm(g2i[64 + t] + g2h[64 + t]);
        float nn = tanhf(g2i[128 + t] + r * g2h[128 + t]);
        float hn = (1.f - z) * nn + z * h1S[t];
        h_next[row * 64 + t] = hn;
        hnS[t] = hn;
    }
    __syncthreads();
    if (emit && t < 256) {
        // Ha = h @ W1a + b_r1 ; Hc = h @ W1c  (readout layer-1 node terms)
        int m = t >> 7, d = t & 127;
        const float* wbase = W_r1 + (m ? 80 * 128 : 0) + d;
        float acc = m ? 0.f : b_r1[d];
#pragma unroll
        for (int k = 0; k < 64; ++k)
            acc = fmaf(hnS[k], wbase[k * 128], acc);
        if (m == 0) Ha[row * 128 + d] = acc;
        else        Hc[row * 128 + d] = acc;
    }
}

// ---------------------------------------------------------------------------
// Factored readout: a1 = relu(Ha[i] + Hc[j] + EW[p]);
// out = relu(a1@W_r2+b2)@W_r3 + b3.  16 pairs per 256-thread block.
__global__ __launch_bounds__(256) void k_read(
    const float* __restrict__ EW, const float* __restrict__ Ha,
    const float* __restrict__ Hc,
    const float* __restrict__ W_r2, const float* __restrict__ b_r2,
    const float* __restrict__ W_r3, const float* __restrict__ b_r3,
    float* __restrict__ out)
{
    __shared__ float HaS[128];
    __shared__ float A1[16 * 128];   // Hc staged, then a1 in place
    int t = threadIdx.x;
    int unit = blockIdx.x;           // row*4 + qp
    int row = unit >> 2, qp = unit & 3;
    int b = row >> 6;

    const float* src = Hc + (size_t)((b << 6) + qp * 16) * 128;
#pragma unroll
    for (int r = 0; r < 2; ++r) {
        int off = (r * 256 + t) * 4;
        *(float4v*)(A1 + off) = *(const float4v*)(src + off);
    }
    if (t < 32)
        *(float4v*)(HaS + t * 4) = *(const float4v*)(Ha + (size_t)row * 128 + t * 4);
    __syncthreads();

    const float* EWrow = EW + (size_t)(row * 64 + qp * 16) * 128;
#pragma unroll
    for (int r = 0; r < 2; ++r) {
        int off = (r * 256 + t) * 4;
        int dd = off & 127;
        float4v hc = *(const float4v*)(A1 + off);
        float4v ha = *(const float4v*)(HaS + dd);
        float4v ew = *(const float4v*)(EWrow + off);
        float4v a;
#pragma unroll
        for (int u = 0; u < 4; ++u) a[u] = fmaxf(hc[u] + ha[u] + ew[u], 0.f);
        *(float4v*)(A1 + off) = a;
    }
    __syncthreads();

    int td = t & 31, pg = t >> 5;
    float4v bb2 = *(const float4v*)(b_r2 + td * 4);
    float4v acc0 = bb2, acc1 = bb2;
    for (int k4 = 0; k4 < 32; ++k4) {
        float4v wA = *(const float4v*)(W_r2 + (k4 * 4 + 0) * 128 + td * 4);
        float4v wB = *(const float4v*)(W_r2 + (k4 * 4 + 1) * 128 + td * 4);
        float4v wC = *(const float4v*)(W_r2 + (k4 * 4 + 2) * 128 + td * 4);
        float4v wD = *(const float4v*)(W_r2 + (k4 * 4 + 3) * 128 + td * 4);
        float4v a0 = *(const float4v*)(A1 + (pg * 2 + 0) * 128 + k4 * 4);
        float4v a1 = *(const float4v*)(A1 + (pg * 2 + 1) * 128 + k4 * 4);
#pragma unroll
        for (int u = 0; u < 4; ++u) {
            acc0[u] = fmaf(a0[0], wA[u], acc0[u]);
            acc0[u] = fmaf(a0[1], wB[u], acc0[u]);
            acc0[u] = fmaf(a0[2], wC[u], acc0[u]);
            acc0[u] = fmaf(a0[3], wD[u], acc0[u]);
            acc1[u] = fmaf(a1[0], wA[u], acc1[u]);
            acc1[u] = fmaf(a1[1], wB[u], acc1[u]);
            acc1[u] = fmaf(a1[2], wC[u], acc1[u]);
            acc1[u] = fmaf(a1[3], wD[u], acc1[u]);
        }
    }

    float4v w3v = *(const float4v*)(W_r3 + td * 4);
    float b3 = b_r3[0];
    float p0 = fmaxf(acc0[0], 0.f) * w3v[0] + fmaxf(acc0[1], 0.f) * w3v[1]
             + fmaxf(acc0[2], 0.f) * w3v[2] + fmaxf(acc0[3], 0.f) * w3v[3];
    float p1 = fmaxf(acc1[0], 0.f) * w3v[0] + fmaxf(acc1[1], 0.f) * w3v[1]
             + fmaxf(acc1[2], 0.f) * w3v[2] + fmaxf(acc1[3], 0.f) * w3v[3];
#pragma unroll
    for (int m = 1; m < 32; m <<= 1) {
        p0 += __shfl_xor(p0, m, 64);
        p1 += __shfl_xor(p1, m, 64);
    }
    if (td == 0) {
        out[row * 64 + qp * 16 + pg * 2 + 0] = p0 + b3;
        out[row * 64 + qp * 16 + pg * 2 + 1] = p1 + b3;
    }
}

// ---------------------------------------------------------------------------
extern "C" void kernel_launch(void* const* d_in, const int* in_sizes, int n_in,
                              void* d_out, int out_size, void* d_ws, size_t ws_size,
                              hipStream_t stream)
{
    const float* edges = (const float*)d_in[0];
    const float* nodes = (const float*)d_in[1];
    // d_in[2] adjacency: unused
    const float* W_en  = (const float*)d_in[3];
    const float* b_en  = (const float*)d_in[4];
    const float* W_agg = (const float*)d_in[5];
    const float* b_agg = (const float*)d_in[6];
    const float* W_ih  = (const float*)d_in[7];
    const float* W_hh  = (const float*)d_in[8];
    const float* b_ih  = (const float*)d_in[9];
    const float* b_hh  = (const float*)d_in[10];
    const float* W_r1  = (const float*)d_in[11];
    const float* b_r1  = (const float*)d_in[12];
    const float* W_r2  = (const float*)d_in[13];
    const float* b_r2  = (const float*)d_in[14];
    const float* W_r3  = (const float*)d_in[15];
    const float* b_r3  = (const float*)d_in[16];

    // workspace layout (~8.7 MB, fully rewritten every call)
    int*   rowcnt  = (int*)d_ws;                         // 256
    int*   rowlist = rowcnt + 256;                       // 16384
    float* hA      = (float*)(rowlist + 16384);          // 16384
    float* hB      = hA + 16384;                         // 16384
    float* Ha      = hB + 16384;                         // 256*128
    float* Hc      = Ha + 256 * 128;                     // 256*128
    float* EW      = Hc + 256 * 128;                     // 16384*128
    float* out     = (float*)d_out;

    k_pre<<<1152, 256, 0, stream>>>(nodes, W_en, b_en, edges, W_r1,
                                    hA, rowcnt, rowlist, EW);
    k_ig<<<256, 512, 0, stream>>>(edges, W_agg, b_agg, W_ih, W_hh, b_ih, b_hh,
                                  rowcnt, rowlist, hA, hB, W_r1, b_r1, Ha, Hc, 0);
    k_ig<<<256, 512, 0, stream>>>(edges, W_agg, b_agg, W_ih, W_hh, b_ih, b_hh,
                                  rowcnt, rowlist, hB, hA, W_r1, b_r1, Ha, Hc, 0);
    k_ig<<<256, 512, 0, stream>>>(edges, W_agg, b_agg, W_ih, W_hh, b_ih, b_hh,
                                  rowcnt, rowlist, hA, hB, W_r1, b_r1, Ha, Hc, 1);
    k_read<<<1024, 256, 0, stream>>>(EW, Ha, Hc, W_r2, b_r2, W_r3, b_r3, out);
}

// Round 10
// 95.633 us; speedup vs baseline: 5.3368x; 1.1000x over previous
//
#include <hip/hip_runtime.h>

typedef float float4v __attribute__((ext_vector_type(4)));

__device__ __forceinline__ float sigm(float x) { return 1.0f / (1.0f + __expf(-x)); }

#define HS_LD 68   // padded leading dim (floats) for staged h in LDS

// ---------------------------------------------------------------------------
// k_pre: blocks 0..63    -> h0 = relu(nodes @ W_en + b_en)
//        blocks 64..127  -> per-row edge compaction + dense feature pack
//        blocks 128..1151-> EW[p][d] = edges[p] @ W1b (W_r1 rows 64..79)
__global__ __launch_bounds__(256) void k_pre(
    const float* __restrict__ nodes, const float* __restrict__ W_en,
    const float* __restrict__ b_en, const float* __restrict__ edges,
    const float* __restrict__ W_r1,
    float* __restrict__ h0, int* __restrict__ rowcnt, int* __restrict__ rowlist,
    float* __restrict__ epack, float* __restrict__ EW)
{
    __shared__ float eS[256];
    int t = threadIdx.x;
    if (blockIdx.x < 64) {
        int idx = blockIdx.x * 256 + t;          // 16384 = B*N*D
        int d = idx & 63, bn = idx >> 6;
        const float* np_ = nodes + bn * 32;
        float acc = b_en[d];
#pragma unroll
        for (int k = 0; k < 32; ++k)
            acc = fmaf(np_[k], W_en[k * 64 + d], acc);
        h0[idx] = fmaxf(acc, 0.f);
    } else if (blockIdx.x < 128) {
        int row = (blockIdx.x - 64) * 4 + (t >> 6);
        int lane = t & 63;
        const float* ep = edges + ((size_t)row * 64 + lane) * 16;
        bool act = ep[0] != 0.f;
        unsigned long long m = __ballot(act);
        if (lane == 0) rowcnt[row] = __popcll(m);
        if (act) {
            int pos = __popcll(m & ((1ull << lane) - 1ull));
            rowlist[row * 64 + pos] = lane;      // ascending j: deterministic
            float* dst = epack + (size_t)row * 1024 + pos * 16;
#pragma unroll
            for (int u = 0; u < 4; ++u)
                *(float4v*)(dst + u * 4) = *(const float4v*)(ep + u * 4);
        }
    } else {
        int base = (blockIdx.x - 128) * 16;      // 16 pairs per block
        eS[t] = edges[(size_t)base * 16 + t];
        __syncthreads();
        int pp = t >> 7, d = t & 127;
#pragma unroll
        for (int pi = 0; pi < 8; ++pi) {
            int pl = pp * 8 + pi;
            float acc = 0.f;
#pragma unroll
            for (int k = 0; k < 16; ++k)
                acc = fmaf(eS[pl * 16 + k], W_r1[(64 + k) * 128 + d], acc);
            EW[(size_t)(base + pl) * 128 + d] = acc;
        }
    }
}

// ---------------------------------------------------------------------------
// Fused iteration kernel: ONE block = ONE receiver row (b,i). 1024 threads:
// thread = (dim = t>>4) x (c4 = t&15, A-columns c4*4..+3).
//   agg[dim] = sum_{s<nE} relu(epack[row,s] @ W_agg + b_agg)[dim,:] . h[b, j_s]
//   then in-block fused 2-cell GRU (+ Ha/Hc emit on last iteration).
// W fragment = 16 float4 (64 VGPR); edge features stream CONTIGUOUSLY from
// epack (uniform, computable addresses -> deep pipelining); j_s comes from a
// register-held rowlist via __shfl (no memory in the dependence chain).
__global__ __launch_bounds__(1024, 1) void k_ig(
    const float* __restrict__ epack, const float* __restrict__ W_agg,
    const float* __restrict__ b_agg,
    const float* __restrict__ W_ih, const float* __restrict__ W_hh,
    const float* __restrict__ b_ih, const float* __restrict__ b_hh,
    const int* __restrict__ rowcnt, const int* __restrict__ rowlist,
    const float* __restrict__ h_cur, float* __restrict__ h_next,
    const float* __restrict__ W_r1, const float* __restrict__ b_r1,
    float* __restrict__ Ha, float* __restrict__ Hc, int emit)
{
    __shared__ float hs[64 * HS_LD];   // h of this batch (17.4 KB)
    __shared__ float xtra[768];        // aggS|g1|h1S|g2i|g2h|hnS

    int t = threadIdx.x;
    int row = blockIdx.x;              // 0..255 = b*64 + i
    int ri = row & 63;
    int b = row >> 6;

    // stage h[b] (64x64): one float4 per thread
    {
        int n = t >> 4, col = (t & 15) * 4;
        *(float4v*)(hs + n * HS_LD + col) =
            *(const float4v*)(h_cur + ((b << 6) + n) * 64 + col);
    }

    int dim = t >> 4, c4 = t & 15, lane = t & 63;

    // resident W fragment (16 float4 = 64 VGPR)
    float4v w[16];
    {
        const float* wp = W_agg + dim * 64 + c4 * 4;
#pragma unroll
        for (int k = 0; k < 16; ++k)
            w[k] = *(const float4v*)(wp + k * 4096);
    }
    float4v bias = *(const float4v*)(b_agg + dim * 64 + c4 * 4);

    int rl = rowlist[row * 64 + lane];     // per-lane slot->j table
    int nE = rowcnt[row];
    __syncthreads();

    // ---- edge loop: contiguous uniform stream, 1-deep prefetch ----
    const float* eb = epack + (size_t)row * 1024;
    float rsum = 0.f;
    float4v n0 = {0,0,0,0}, n1 = n0, n2 = n0, n3 = n0;
    if (nE > 0) {
        n0 = *(const float4v*)(eb);      n1 = *(const float4v*)(eb + 4);
        n2 = *(const float4v*)(eb + 8);  n3 = *(const float4v*)(eb + 12);
    }
    for (int idx = 0; idx < nE; ++idx) {
        float4v e0 = n0, e1 = n1, e2 = n2, e3 = n3;
        if (idx + 1 < nE) {
            const float* ep = eb + (idx + 1) * 16;
            n0 = *(const float4v*)(ep);      n1 = *(const float4v*)(ep + 4);
            n2 = *(const float4v*)(ep + 8);  n3 = *(const float4v*)(ep + 12);
        }
        int ej = __shfl(rl, idx, 64);      // register-only chain
        float4v a = bias;
#pragma unroll
        for (int k = 0; k < 4; ++k) {
#pragma unroll
            for (int u = 0; u < 4; ++u) a[u] = fmaf(e0[k], w[k][u], a[u]);
        }
#pragma unroll
        for (int k = 0; k < 4; ++k) {
#pragma unroll
            for (int u = 0; u < 4; ++u) a[u] = fmaf(e1[k], w[4 + k][u], a[u]);
        }
#pragma unroll
        for (int k = 0; k < 4; ++k) {
#pragma unroll
            for (int u = 0; u < 4; ++u) a[u] = fmaf(e2[k], w[8 + k][u], a[u]);
        }
#pragma unroll
        for (int k = 0; k < 4; ++k) {
#pragma unroll
            for (int u = 0; u < 4; ++u) a[u] = fmaf(e3[k], w[12 + k][u], a[u]);
        }
        float4v hv = *(const float4v*)(hs + ej * HS_LD + c4 * 4);
#pragma unroll
        for (int u = 0; u < 4; ++u)
            rsum = fmaf(fmaxf(a[u], 0.f), hv[u], rsum);
    }
    // reduce over the 16 c4-lanes of each dim group
#pragma unroll
    for (int m = 1; m < 16; m <<= 1) rsum += __shfl_xor(rsum, m, 64);
    float* aggS = xtra;                // 64
    if (c4 == 0) aggS[dim] = rsum;
    __syncthreads();

    // ---- fused 2-cell GRU ----
    float* g1  = xtra + 64;            // 192
    float* h1S = xtra + 256;           // 64
    float* g2i = xtra + 320;           // 192
    float* g2h = xtra + 512;           // 192
    float* hnS = xtra + 704;           // 64
    const float* hrow = hs + ri * HS_LD;

    if (t < 192) {
        float g = b_ih[t];
        const float* wr = W_ih + t * 64;
#pragma unroll
        for (int k = 0; k < 64; ++k) g = fmaf(hrow[k], wr[k], g);
        g1[t] = g;
    }
    __syncthreads();
    if (t < 64) {
        float r1 = sigm(g1[t] + b_hh[t]);
        float z1 = sigm(g1[64 + t] + b_hh[64 + t]);
        float nn1 = tanhf(g1[128 + t] + r1 * b_hh[128 + t]);
        h1S[t] = (1.f - z1) * nn1;
    }
    __syncthreads();
    if (t < 192) {
        float gi = b_ih[t];
        float gh = b_hh[t];
        const float* wri = W_ih + t * 64;
        const float* wrh = W_hh + t * 64;
#pragma unroll
        for (int k = 0; k < 64; ++k) {
            gi = fmaf(aggS[k], wri[k], gi);
            gh = fmaf(h1S[k], wrh[k], gh);
        }
        g2i[t] = gi; g2h[t] = gh;
    }
    __syncthreads();
    if (t < 64) {
        float r = sigm(g2i[t] + g2h[t]);
        float z = sigm(g2i[64 + t] + g2h[64 + t]);
        float nn = tanhf(g2i[128 + t] + r * g2h[128 + t]);
        float hn = (1.f - z) * nn + z * h1S[t];
        h_next[row * 64 + t] = hn;
        hnS[t] = hn;
    }
    __syncthreads();
    if (emit && t < 256) {
        // Ha = h @ W1a + b_r1 ; Hc = h @ W1c  (readout layer-1 node terms)
        int m = t >> 7, d = t & 127;
        const float* wbase = W_r1 + (m ? 80 * 128 : 0) + d;
        float acc = m ? 0.f : b_r1[d];
#pragma unroll
        for (int k = 0; k < 64; ++k)
            acc = fmaf(hnS[k], wbase[k * 128], acc);
        if (m == 0) Ha[row * 128 + d] = acc;
        else        Hc[row * 128 + d] = acc;
    }
}

// ---------------------------------------------------------------------------
// Factored readout: a1 = relu(Ha[i] + Hc[j] + EW[p]);
// out = relu(a1@W_r2+b2)@W_r3 + b3.   32 pairs per 256-thread block
// (4 pairs x 4 dims per thread -> W_r2 issue traffic halved vs 16-pair).
__global__ __launch_bounds__(256) void k_read(
    const float* __restrict__ EW, const float* __restrict__ Ha,
    const float* __restrict__ Hc,
    const float* __restrict__ W_r2, const float* __restrict__ b_r2,
    const float* __restrict__ W_r3, const float* __restrict__ b_r3,
    float* __restrict__ out)
{
    __shared__ float HaS[128];
    __shared__ float A1[32 * 128];   // 16 KB: Hc staged, then a1 in place
    int t = threadIdx.x;
    int unit = blockIdx.x;           // row*2 + qp
    int row = unit >> 1, qp = unit & 1;
    int b = row >> 6;

    const float* src = Hc + (size_t)((b << 6) + qp * 32) * 128;
#pragma unroll
    for (int r = 0; r < 4; ++r) {
        int off = (r * 256 + t) * 4;
        *(float4v*)(A1 + off) = *(const float4v*)(src + off);
    }
    if (t < 32)
        *(float4v*)(HaS + t * 4) = *(const float4v*)(Ha + (size_t)row * 128 + t * 4);
    __syncthreads();

    const float* EWrow = EW + (size_t)(row * 64 + qp * 32) * 128;
#pragma unroll
    for (int r = 0; r < 4; ++r) {
        int off = (r * 256 + t) * 4;
        int dd = off & 127;
        float4v hc = *(const float4v*)(A1 + off);
        float4v ha = *(const float4v*)(HaS + dd);
        float4v ew = *(const float4v*)(EWrow + off);
        float4v a;
#pragma unroll
        for (int u = 0; u < 4; ++u) a[u] = fmaxf(hc[u] + ha[u] + ew[u], 0.f);
        *(float4v*)(A1 + off) = a;
    }
    __syncthreads();

    int td = t & 31, pg = t >> 5;    // dims td*4..+3 ; pairs pg*4..+3
    float4v bb2 = *(const float4v*)(b_r2 + td * 4);
    float4v acc0 = bb2, acc1 = bb2, acc2 = bb2, acc3 = bb2;
    for (int k4 = 0; k4 < 32; ++k4) {
        float4v wA = *(const float4v*)(W_r2 + (k4 * 4 + 0) * 128 + td * 4);
        float4v wB = *(const float4v*)(W_r2 + (k4 * 4 + 1) * 128 + td * 4);
        float4v wC = *(const float4v*)(W_r2 + (k4 * 4 + 2) * 128 + td * 4);
        float4v wD = *(const float4v*)(W_r2 + (k4 * 4 + 3) * 128 + td * 4);
        float4v a0 = *(const float4v*)(A1 + (pg * 4 + 0) * 128 + k4 * 4);
        float4v a1 = *(const float4v*)(A1 + (pg * 4 + 1) * 128 + k4 * 4);
        float4v a2 = *(const float4v*)(A1 + (pg * 4 + 2) * 128 + k4 * 4);
        float4v a3 = *(const float4v*)(A1 + (pg * 4 + 3) * 128 + k4 * 4);
#pragma unroll
        for (int u = 0; u < 4; ++u) {
            acc0[u] = fmaf(a0[0], wA[u], acc0[u]);
            acc0[u] = fmaf(a0[1], wB[u], acc0[u]);
            acc0[u] = fmaf(a0[2], wC[u], acc0[u]);
            acc0[u] = fmaf(a0[3], wD[u], acc0[u]);
            acc1[u] = fmaf(a1[0], wA[u], acc1[u]);
            acc1[u] = fmaf(a1[1], wB[u], acc1[u]);
            acc1[u] = fmaf(a1[2], wC[u], acc1[u]);
            acc1[u] = fmaf(a1[3], wD[u], acc1[u]);
            acc2[u] = fmaf(a2[0], wA[u], acc2[u]);
            acc2[u] = fmaf(a2[1], wB[u], acc2[u]);
            acc2[u] = fmaf(a2[2], wC[u], acc2[u]);
            acc2[u] = fmaf(a2[3], wD[u], acc2[u]);
            acc3[u] = fmaf(a3[0], wA[u], acc3[u]);
            acc3[u] = fmaf(a3[1], wB[u], acc3[u]);
            acc3[u] = fmaf(a3[2], wC[u], acc3[u]);
            acc3[u] = fmaf(a3[3], wD[u], acc3[u]);
        }
    }

    float4v w3v = *(const float4v*)(W_r3 + td * 4);
    float b3 = b_r3[0];
    float p0 = fmaxf(acc0[0], 0.f) * w3v[0] + fmaxf(acc0[1], 0.f) * w3v[1]
             + fmaxf(acc0[2], 0.f) * w3v[2] + fmaxf(acc0[3], 0.f) * w3v[3];
    float p1 = fmaxf(acc1[0], 0.f) * w3v[0] + fmaxf(acc1[1], 0.f) * w3v[1]
             + fmaxf(acc1[2], 0.f) * w3v[2] + fmaxf(acc1[3], 0.f) * w3v[3];
    float p2 = fmaxf(acc2[0], 0.f) * w3v[0] + fmaxf(acc2[1], 0.f) * w3v[1]
             + fmaxf(acc2[2], 0.f) * w3v[2] + fmaxf(acc2[3], 0.f) * w3v[3];
    float p3 = fmaxf(acc3[0], 0.f) * w3v[0] + fmaxf(acc3[1], 0.f) * w3v[1]
             + fmaxf(acc3[2], 0.f) * w3v[2] + fmaxf(acc3[3], 0.f) * w3v[3];
#pragma unroll
    for (int m = 1; m < 32; m <<= 1) {
        p0 += __shfl_xor(p0, m, 64);
        p1 += __shfl_xor(p1, m, 64);
        p2 += __shfl_xor(p2, m, 64);
        p3 += __shfl_xor(p3, m, 64);
    }
    if (td == 0) {
        int obase = row * 64 + qp * 32 + pg * 4;
        out[obase + 0] = p0 + b3;
        out[obase + 1] = p1 + b3;
        out[obase + 2] = p2 + b3;
        out[obase + 3] = p3 + b3;
    }
}

// ---------------------------------------------------------------------------
extern "C" void kernel_launch(void* const* d_in, const int* in_sizes, int n_in,
                              void* d_out, int out_size, void* d_ws, size_t ws_size,
                              hipStream_t stream)
{
    const float* edges = (const float*)d_in[0];
    const float* nodes = (const float*)d_in[1];
    // d_in[2] adjacency: unused
    const float* W_en  = (const float*)d_in[3];
    const float* b_en  = (const float*)d_in[4];
    const float* W_agg = (const float*)d_in[5];
    const float* b_agg = (const float*)d_in[6];
    const float* W_ih  = (const float*)d_in[7];
    const float* W_hh  = (const float*)d_in[8];
    const float* b_ih  = (const float*)d_in[9];
    const float* b_hh  = (const float*)d_in[10];
    const float* W_r1  = (const float*)d_in[11];
    const float* b_r1  = (const float*)d_in[12];
    const float* W_r2  = (const float*)d_in[13];
    const float* b_r2  = (const float*)d_in[14];
    const float* W_r3  = (const float*)d_in[15];
    const float* b_r3  = (const float*)d_in[16];

    // workspace layout (~9.8 MB, fully rewritten every call)
    int*   rowcnt  = (int*)d_ws;                         // 256
    int*   rowlist = rowcnt + 256;                       // 16384
    float* hA      = (float*)(rowlist + 16384);          // 16384
    float* hB      = hA + 16384;                         // 16384
    float* Ha      = hB + 16384;                         // 256*128
    float* Hc      = Ha + 256 * 128;                     // 256*128
    float* epack   = Hc + 256 * 128;                     // 256*1024
    float* EW      = epack + 256 * 1024;                 // 16384*128
    float* out     = (float*)d_out;

    k_pre<<<1152, 256, 0, stream>>>(nodes, W_en, b_en, edges, W_r1,
                                    hA, rowcnt, rowlist, epack, EW);
    k_ig<<<256, 1024, 0, stream>>>(epack, W_agg, b_agg, W_ih, W_hh, b_ih, b_hh,
                                   rowcnt, rowlist, hA, hB, W_r1, b_r1, Ha, Hc, 0);
    k_ig<<<256, 1024, 0, stream>>>(epack, W_agg, b_agg, W_ih, W_hh, b_ih, b_hh,
                                   rowcnt, rowlist, hB, hA, W_r1, b_r1, Ha, Hc, 0);
    k_ig<<<256, 1024, 0, stream>>>(epack, W_agg, b_agg, W_ih, W_hh, b_ih, b_hh,
                                   rowcnt, rowlist, hA, hB, W_r1, b_r1, Ha, Hc, 1);
    k_read<<<512, 256, 0, stream>>>(EW, Ha, Hc, W_r2, b_r2, W_r3, b_r3, out);
}

// Round 11
// 83.190 us; speedup vs baseline: 6.1351x; 1.1496x over previous
//
#include <hip/hip_runtime.h>

typedef float float4v __attribute__((ext_vector_type(4)));

__device__ __forceinline__ float sigm(float x) { return 1.0f / (1.0f + __expf(-x)); }

#define HS_LD 68   // padded leading dim (floats) for staged h in LDS

// ---------------------------------------------------------------------------
// Self-sufficient iteration kernel. ONE block = ONE receiver row (b,i),
// 1024 threads = (dim = t>>4) x (c4 = t&15 -> A-columns c4*4..+3).
//  - it0: computes h0 = relu(nodes@W_en+b_en) for the whole batch in LDS
//         (redundant per block; no global h0 round-trip). else loads h_cur.
//  - packs its own row's active edges into LDS (ballot, ascending j).
//  - agg[dim] = sum_s relu(e_s @ W_agg + b_agg)[dim,:] . h[b, j_s]
//  - fused 2-cell GRU -> h_next; emit: Ha/Hc readout layer-1 node terms.
__global__ __launch_bounds__(1024) void k_it(
    const float* __restrict__ edges, const float* __restrict__ nodes,
    const float* __restrict__ W_en, const float* __restrict__ b_en,
    const float* __restrict__ W_agg, const float* __restrict__ b_agg,
    const float* __restrict__ W_ih, const float* __restrict__ W_hh,
    const float* __restrict__ b_ih, const float* __restrict__ b_hh,
    const float* __restrict__ h_cur, float* __restrict__ h_next,
    const float* __restrict__ W_r1, const float* __restrict__ b_r1,
    float* __restrict__ Ha, float* __restrict__ Hc, int it0, int emit)
{
    __shared__ float hs[64 * HS_LD];   // h of this batch (17.4 KB)
    __shared__ float eL[64 * 16];      // packed active-edge features (4 KB)
    __shared__ int   jn[64];           // slot -> sender j
    __shared__ int   nES;
    __shared__ float xtra[768];        // aggS|g1|h1S|g2i|g2h|hnS

    int t = threadIdx.x;
    int row = blockIdx.x;              // 0..255 = b*64 + i
    int ri = row & 63;
    int b = row >> 6;

    // ---- stage h[b] into LDS: compute h0 (it0) or load h_cur ----
    if (it0) {
#pragma unroll
        for (int q = 0; q < 4; ++q) {
            int idx = q * 1024 + t;            // 4096 = 64 nodes x 64 dims
            int n = idx >> 6, d = idx & 63;    // n wave-uniform -> scalar loads
            const float* np_ = nodes + ((b << 6) + n) * 32;
            float acc = b_en[d];
#pragma unroll
            for (int k = 0; k < 32; ++k)
                acc = fmaf(np_[k], W_en[k * 64 + d], acc);
            hs[n * HS_LD + d] = fmaxf(acc, 0.f);
        }
    } else {
        int n = t >> 4, col = (t & 15) * 4;
        *(float4v*)(hs + n * HS_LD + col) =
            *(const float4v*)(h_cur + ((b << 6) + n) * 64 + col);
    }

    // ---- pack own row's active edges (wave 0 only; ascending j) ----
    if (t < 64) {
        const float* ep = edges + ((size_t)row * 64 + t) * 16;
        float f0 = ep[0];
        unsigned long long m = __ballot(f0 != 0.f);
        if (t == 0) nES = __popcll(m);
        if (f0 != 0.f) {
            int pos = __popcll(m & ((1ull << t) - 1ull));
            jn[pos] = t;
            float* dst = eL + pos * 16;
#pragma unroll
            for (int u = 0; u < 4; ++u)
                *(float4v*)(dst + u * 4) = *(const float4v*)(ep + u * 4);
        }
    }

    // ---- resident W fragment (16 float4 = 64 VGPR) ----
    int dim = t >> 4, c4 = t & 15;
    float4v w[16];
    {
        const float* wp = W_agg + dim * 64 + c4 * 4;
#pragma unroll
        for (int k = 0; k < 16; ++k)
            w[k] = *(const float4v*)(wp + k * 4096);
    }
    float4v bias = *(const float4v*)(b_agg + dim * 64 + c4 * 4);

    __syncthreads();
    int nE = nES;

    // ---- edge loop: all operands in LDS, uniform computable addresses ----
    float rsum = 0.f;
    for (int s = 0; s < nE; ++s) {
        const float* eP = eL + s * 16;
        float4v e0 = *(const float4v*)(eP);
        float4v e1 = *(const float4v*)(eP + 4);
        float4v e2 = *(const float4v*)(eP + 8);
        float4v e3 = *(const float4v*)(eP + 12);
        int ej = jn[s];
        float4v a = bias;
#pragma unroll
        for (int k = 0; k < 4; ++k) {
#pragma unroll
            for (int u = 0; u < 4; ++u) a[u] = fmaf(e0[k], w[k][u], a[u]);
        }
#pragma unroll
        for (int k = 0; k < 4; ++k) {
#pragma unroll
            for (int u = 0; u < 4; ++u) a[u] = fmaf(e1[k], w[4 + k][u], a[u]);
        }
#pragma unroll
        for (int k = 0; k < 4; ++k) {
#pragma unroll
            for (int u = 0; u < 4; ++u) a[u] = fmaf(e2[k], w[8 + k][u], a[u]);
        }
#pragma unroll
        for (int k = 0; k < 4; ++k) {
#pragma unroll
            for (int u = 0; u < 4; ++u) a[u] = fmaf(e3[k], w[12 + k][u], a[u]);
        }
        float4v hv = *(const float4v*)(hs + ej * HS_LD + c4 * 4);
#pragma unroll
        for (int u = 0; u < 4; ++u)
            rsum = fmaf(fmaxf(a[u], 0.f), hv[u], rsum);
    }
    // reduce over the 16 c4-lanes
#pragma unroll
    for (int m = 1; m < 16; m <<= 1) rsum += __shfl_xor(rsum, m, 64);
    float* aggS = xtra;
    if (c4 == 0) aggS[dim] = rsum;
    __syncthreads();

    // ---- fused 2-cell GRU ----
    float* g1  = xtra + 64;
    float* h1S = xtra + 256;
    float* g2i = xtra + 320;
    float* g2h = xtra + 512;
    float* hnS = xtra + 704;
    const float* hrow = hs + ri * HS_LD;

    if (t < 192) {
        float g = b_ih[t];
        const float* wr = W_ih + t * 64;
#pragma unroll
        for (int k = 0; k < 64; ++k) g = fmaf(hrow[k], wr[k], g);
        g1[t] = g;
    }
    __syncthreads();
    if (t < 64) {
        float r1 = sigm(g1[t] + b_hh[t]);
        float z1 = sigm(g1[64 + t] + b_hh[64 + t]);
        float nn1 = tanhf(g1[128 + t] + r1 * b_hh[128 + t]);
        h1S[t] = (1.f - z1) * nn1;
    }
    __syncthreads();
    if (t < 192) {
        float gi = b_ih[t];
        float gh = b_hh[t];
        const float* wri = W_ih + t * 64;
        const float* wrh = W_hh + t * 64;
#pragma unroll
        for (int k = 0; k < 64; ++k) {
            gi = fmaf(aggS[k], wri[k], gi);
            gh = fmaf(h1S[k], wrh[k], gh);
        }
        g2i[t] = gi; g2h[t] = gh;
    }
    __syncthreads();
    if (t < 64) {
        float r = sigm(g2i[t] + g2h[t]);
        float z = sigm(g2i[64 + t] + g2h[64 + t]);
        float nn = tanhf(g2i[128 + t] + r * g2h[128 + t]);
        float hn = (1.f - z) * nn + z * h1S[t];
        h_next[row * 64 + t] = hn;
        hnS[t] = hn;
    }
    __syncthreads();
    if (emit && t < 256) {
        // Ha = h @ W1a + b_r1 (W_r1 rows 0..63); Hc = h @ W1c (rows 80..143)
        int m = t >> 7, d = t & 127;
        const float* wbase = W_r1 + (m ? 80 * 128 : 0) + d;
        float acc = m ? 0.f : b_r1[d];
#pragma unroll
        for (int k = 0; k < 64; ++k)
            acc = fmaf(hnS[k], wbase[k * 128], acc);
        if (m == 0) Ha[row * 128 + d] = acc;
        else        Hc[row * 128 + d] = acc;
    }
}

// ---------------------------------------------------------------------------
// Factored readout with inline edge term:
//   a1 = relu(Ha[i] + Hc[j] + e_p @ W1b);  out = relu(a1@W_r2+b2)@W_r3 + b3
// 32 pairs per 256-thread block (4 pairs x 4 dims per thread).
__global__ __launch_bounds__(256) void k_read(
    const float* __restrict__ edges,
    const float* __restrict__ Ha, const float* __restrict__ Hc,
    const float* __restrict__ W_r1,
    const float* __restrict__ W_r2, const float* __restrict__ b_r2,
    const float* __restrict__ W_r3, const float* __restrict__ b_r3,
    float* __restrict__ out)
{
    __shared__ float HaS[128];
    __shared__ float eS[32 * 16];    // this unit's 32 edge rows (2 KB)
    __shared__ float A1[32 * 128];   // Hc staged, then a1 in place (16 KB)
    int t = threadIdx.x;
    int unit = blockIdx.x;           // row*2 + qp
    int row = unit >> 1, qp = unit & 1;
    int b = row >> 6;

    const float* src = Hc + (size_t)((b << 6) + qp * 32) * 128;
#pragma unroll
    for (int r = 0; r < 4; ++r) {
        int off = (r * 256 + t) * 4;
        *(float4v*)(A1 + off) = *(const float4v*)(src + off);
    }
    if (t < 32)
        *(float4v*)(HaS + t * 4) = *(const float4v*)(Ha + (size_t)row * 128 + t * 4);
    if (t < 128)   // edges of pairs qp*32..+32: contiguous 512 floats
        *(float4v*)(eS + t * 4) =
            *(const float4v*)(edges + ((size_t)row * 64 + qp * 32) * 16 + t * 4);
    __syncthreads();

    int td = t & 31, pg = t >> 5;    // dims td*4..+3 ; pairs pg*4..+3

    // layer-1 edge term: ew[pi][u] = sum_k e[p][k] * W1b[k][td*4+u]
    float4v ew0 = {0,0,0,0}, ew1 = ew0, ew2 = ew0, ew3 = ew0;
#pragma unroll
    for (int k = 0; k < 16; ++k) {
        float4v wk = *(const float4v*)(W_r1 + (64 + k) * 128 + td * 4);
        float e0 = eS[(pg * 4 + 0) * 16 + k];
        float e1 = eS[(pg * 4 + 1) * 16 + k];
        float e2 = eS[(pg * 4 + 2) * 16 + k];
        float e3 = eS[(pg * 4 + 3) * 16 + k];
#pragma unroll
        for (int u = 0; u < 4; ++u) {
            ew0[u] = fmaf(e0, wk[u], ew0[u]);
            ew1[u] = fmaf(e1, wk[u], ew1[u]);
            ew2[u] = fmaf(e2, wk[u], ew2[u]);
            ew3[u] = fmaf(e3, wk[u], ew3[u]);
        }
    }
    float4v ha = *(const float4v*)(HaS + td * 4);
#pragma unroll
    for (int pi = 0; pi < 4; ++pi) {
        float4v ew = (pi == 0) ? ew0 : (pi == 1) ? ew1 : (pi == 2) ? ew2 : ew3;
        float* slot = A1 + (pg * 4 + pi) * 128 + td * 4;
        float4v hc = *(const float4v*)slot;
        float4v a;
#pragma unroll
        for (int u = 0; u < 4; ++u) a[u] = fmaxf(hc[u] + ha[u] + ew[u], 0.f);
        *(float4v*)slot = a;
    }
    __syncthreads();

    // layer 2
    float4v bb2 = *(const float4v*)(b_r2 + td * 4);
    float4v acc0 = bb2, acc1 = bb2, acc2 = bb2, acc3 = bb2;
    for (int k4 = 0; k4 < 32; ++k4) {
        float4v wA = *(const float4v*)(W_r2 + (k4 * 4 + 0) * 128 + td * 4);
        float4v wB = *(const float4v*)(W_r2 + (k4 * 4 + 1) * 128 + td * 4);
        float4v wC = *(const float4v*)(W_r2 + (k4 * 4 + 2) * 128 + td * 4);
        float4v wD = *(const float4v*)(W_r2 + (k4 * 4 + 3) * 128 + td * 4);
        float4v a0 = *(const float4v*)(A1 + (pg * 4 + 0) * 128 + k4 * 4);
        float4v a1 = *(const float4v*)(A1 + (pg * 4 + 1) * 128 + k4 * 4);
        float4v a2 = *(const float4v*)(A1 + (pg * 4 + 2) * 128 + k4 * 4);
        float4v a3 = *(const float4v*)(A1 + (pg * 4 + 3) * 128 + k4 * 4);
#pragma unroll
        for (int u = 0; u < 4; ++u) {
            acc0[u] = fmaf(a0[0], wA[u], acc0[u]);
            acc0[u] = fmaf(a0[1], wB[u], acc0[u]);
            acc0[u] = fmaf(a0[2], wC[u], acc0[u]);
            acc0[u] = fmaf(a0[3], wD[u], acc0[u]);
            acc1[u] = fmaf(a1[0], wA[u], acc1[u]);
            acc1[u] = fmaf(a1[1], wB[u], acc1[u]);
            acc1[u] = fmaf(a1[2], wC[u], acc1[u]);
            acc1[u] = fmaf(a1[3], wD[u], acc1[u]);
            acc2[u] = fmaf(a2[0], wA[u], acc2[u]);
            acc2[u] = fmaf(a2[1], wB[u], acc2[u]);
            acc2[u] = fmaf(a2[2], wC[u], acc2[u]);
            acc2[u] = fmaf(a2[3], wD[u], acc2[u]);
            acc3[u] = fmaf(a3[0], wA[u], acc3[u]);
            acc3[u] = fmaf(a3[1], wB[u], acc3[u]);
            acc3[u] = fmaf(a3[2], wC[u], acc3[u]);
            acc3[u] = fmaf(a3[3], wD[u], acc3[u]);
        }
    }

    // layer 3
    float4v w3v = *(const float4v*)(W_r3 + td * 4);
    float b3 = b_r3[0];
    float p0 = fmaxf(acc0[0], 0.f) * w3v[0] + fmaxf(acc0[1], 0.f) * w3v[1]
             + fmaxf(acc0[2], 0.f) * w3v[2] + fmaxf(acc0[3], 0.f) * w3v[3];
    float p1 = fmaxf(acc1[0], 0.f) * w3v[0] + fmaxf(acc1[1], 0.f) * w3v[1]
             + fmaxf(acc1[2], 0.f) * w3v[2] + fmaxf(acc1[3], 0.f) * w3v[3];
    float p2 = fmaxf(acc2[0], 0.f) * w3v[0] + fmaxf(acc2[1], 0.f) * w3v[1]
             + fmaxf(acc2[2], 0.f) * w3v[2] + fmaxf(acc2[3], 0.f) * w3v[3];
    float p3 = fmaxf(acc3[0], 0.f) * w3v[0] + fmaxf(acc3[1], 0.f) * w3v[1]
             + fmaxf(acc3[2], 0.f) * w3v[2] + fmaxf(acc3[3], 0.f) * w3v[3];
#pragma unroll
    for (int m = 1; m < 32; m <<= 1) {
        p0 += __shfl_xor(p0, m, 64);
        p1 += __shfl_xor(p1, m, 64);
        p2 += __shfl_xor(p2, m, 64);
        p3 += __shfl_xor(p3, m, 64);
    }
    if (td == 0) {
        int obase = row * 64 + qp * 32 + pg * 4;
        out[obase + 0] = p0 + b3;
        out[obase + 1] = p1 + b3;
        out[obase + 2] = p2 + b3;
        out[obase + 3] = p3 + b3;
    }
}

// ---------------------------------------------------------------------------
extern "C" void kernel_launch(void* const* d_in, const int* in_sizes, int n_in,
                              void* d_out, int out_size, void* d_ws, size_t ws_size,
                              hipStream_t stream)
{
    const float* edges = (const float*)d_in[0];
    const float* nodes = (const float*)d_in[1];
    // d_in[2] adjacency: unused
    const float* W_en  = (const float*)d_in[3];
    const float* b_en  = (const float*)d_in[4];
    const float* W_agg = (const float*)d_in[5];
    const float* b_agg = (const float*)d_in[6];
    const float* W_ih  = (const float*)d_in[7];
    const float* W_hh  = (const float*)d_in[8];
    const float* b_ih  = (const float*)d_in[9];
    const float* b_hh  = (const float*)d_in[10];
    const float* W_r1  = (const float*)d_in[11];
    const float* b_r1  = (const float*)d_in[12];
    const float* W_r2  = (const float*)d_in[13];
    const float* b_r2  = (const float*)d_in[14];
    const float* W_r3  = (const float*)d_in[15];
    const float* b_r3  = (const float*)d_in[16];

    // workspace (~400 KB, fully rewritten every call)
    float* hA = (float*)d_ws;          // 16384
    float* hB = hA + 16384;            // 16384
    float* Ha = hB + 16384;            // 256*128
    float* Hc = Ha + 256 * 128;        // 256*128
    float* out = (float*)d_out;

    k_it<<<256, 1024, 0, stream>>>(edges, nodes, W_en, b_en, W_agg, b_agg,
                                   W_ih, W_hh, b_ih, b_hh, hA, hA,
                                   W_r1, b_r1, Ha, Hc, 1, 0);
    k_it<<<256, 1024, 0, stream>>>(edges, nodes, W_en, b_en, W_agg, b_agg,
                                   W_ih, W_hh, b_ih, b_hh, hA, hB,
                                   W_r1, b_r1, Ha, Hc, 0, 0);
    k_it<<<256, 1024, 0, stream>>>(edges, nodes, W_en, b_en, W_agg, b_agg,
                                   W_ih, W_hh, b_ih, b_hh, hB, hA,
                                   W_r1, b_r1, Ha, Hc, 0, 1);
    k_read<<<512, 256, 0, stream>>>(edges, Ha, Hc, W_r1, W_r2, b_r2,
                                    W_r3, b_r3, out);
}